// Round 1
// baseline (14915.199 us; speedup 1.0000x reference)
//
#include <hip/hip_runtime.h>

// TGCN: 2-layer, T=12, F=8, H=64. gconv is linear => split concat into
// precomputed gconv(x_t) (all t at once) + per-step gconv(h)/gconv(r*h).

#define FT 96      // F*T
#define H 64
#define TSTEPS 12

// scatter: out[dst,c] += w * feat[src,c], C=64. One thread per (edge,channel);
// each 64-lane wave covers exactly one edge (broadcast src/dst/w loads).
__global__ void scatter64(const float* __restrict__ feat, const int* __restrict__ src,
                          const int* __restrict__ dst, const float* __restrict__ w,
                          float* __restrict__ out, int E) {
    int i = blockIdx.x * blockDim.x + threadIdx.x;
    int e = i >> 6;
    if (e >= E) return;
    int c = i & 63;
    float v = w[e] * feat[src[e] * 64 + c];
    atomicAdd(&out[dst[e] * 64 + c], v);
}

// scatter over the raw x tensor: 96 channels per node (F*T layout, contiguous).
__global__ void scatter96(const float* __restrict__ x, const int* __restrict__ src,
                          const int* __restrict__ dst, const float* __restrict__ w,
                          float* __restrict__ out, int E) {
    int i = blockIdx.x * blockDim.x + threadIdx.x;
    if (i >= E * FT) return;
    int e = i / FT;
    int c = i - e * FT;
    float v = w[e] * x[src[e] * FT + c];
    atomicAdd(&out[dst[e] * FT + c], v);
}

// Layer 0 gates: rz = sigmoid(aggX_t @ Wg[0:8] + aggH @ Wg[8:72] + bg)
// writes RH = r*h (cols 0..63) and Z = z (cols 64..127)
__global__ __launch_bounds__(512) void gate0_k(
    const float* __restrict__ aggX, int t, const float* __restrict__ aggH,
    const float* __restrict__ Wg, const float* __restrict__ bg,
    const float* __restrict__ h, float* __restrict__ Z, float* __restrict__ RH, int N) {
    __shared__ float sW[72 * 128];  // 36 KB
    for (int j = threadIdx.x; j < 72 * 128; j += 512) sW[j] = Wg[j];
    __syncthreads();
    int n = blockIdx.x * 4 + (threadIdx.x >> 7);
    int col = threadIdx.x & 127;
    if (n >= N) return;
    float acc = bg[col];
    const float* ax = aggX + n * FT;
#pragma unroll
    for (int f = 0; f < 8; ++f) acc += ax[f * TSTEPS + t] * sW[f * 128 + col];
    const float* ah = aggH + n * 64;
#pragma unroll 8
    for (int k = 0; k < 64; ++k) acc += ah[k] * sW[(8 + k) * 128 + col];
    float s = 1.0f / (1.0f + __expf(-acc));
    if (col < 64) RH[n * 64 + col] = s * h[n * 64 + col];
    else          Z[n * 64 + (col - 64)] = s;
}

// Layer 0 candidate + state update: c = tanh(...); h = z*h + (1-z)*c
__global__ __launch_bounds__(512) void cand0_k(
    const float* __restrict__ aggX, int t, const float* __restrict__ aggRH,
    const float* __restrict__ Wc, const float* __restrict__ bc,
    const float* __restrict__ Z, float* __restrict__ h, int N) {
    __shared__ float sW[72 * 64];  // 18 KB
    for (int j = threadIdx.x; j < 72 * 64; j += 512) sW[j] = Wc[j];
    __syncthreads();
    int n = blockIdx.x * 8 + (threadIdx.x >> 6);
    int col = threadIdx.x & 63;
    if (n >= N) return;
    float acc = bc[col];
    const float* ax = aggX + n * FT;
#pragma unroll
    for (int f = 0; f < 8; ++f) acc += ax[f * TSTEPS + t] * sW[f * 64 + col];
    const float* ar = aggRH + n * 64;
#pragma unroll 8
    for (int k = 0; k < 64; ++k) acc += ar[k] * sW[(8 + k) * 64 + col];
    float c = tanhf(acc);
    float z = Z[n * 64 + col];
    float hv = h[n * 64 + col];
    h[n * 64 + col] = z * hv + (1.0f - z) * c;
}

// Layer 1 gates: inputs aggA = gconv(h0_new), aggB = gconv(h1)
__global__ __launch_bounds__(512) void gate1_k(
    const float* __restrict__ aggA, const float* __restrict__ aggB,
    const float* __restrict__ Wg, const float* __restrict__ bg,
    const float* __restrict__ h, float* __restrict__ Z, float* __restrict__ RH, int N) {
    __shared__ float sW[128 * 128];  // 64 KB
    for (int j = threadIdx.x; j < 128 * 128; j += 512) sW[j] = Wg[j];
    __syncthreads();
    int n = blockIdx.x * 4 + (threadIdx.x >> 7);
    int col = threadIdx.x & 127;
    if (n >= N) return;
    float acc = bg[col];
    const float* aa = aggA + n * 64;
    const float* ab = aggB + n * 64;
#pragma unroll 8
    for (int k = 0; k < 64; ++k) acc += aa[k] * sW[k * 128 + col];
#pragma unroll 8
    for (int k = 0; k < 64; ++k) acc += ab[k] * sW[(64 + k) * 128 + col];
    float s = 1.0f / (1.0f + __expf(-acc));
    if (col < 64) RH[n * 64 + col] = s * h[n * 64 + col];
    else          Z[n * 64 + (col - 64)] = s;
}

__global__ __launch_bounds__(512) void cand1_k(
    const float* __restrict__ aggA, const float* __restrict__ aggRH,
    const float* __restrict__ Wc, const float* __restrict__ bc,
    const float* __restrict__ Z, float* __restrict__ h, int N) {
    __shared__ float sW[128 * 64];  // 32 KB
    for (int j = threadIdx.x; j < 128 * 64; j += 512) sW[j] = Wc[j];
    __syncthreads();
    int n = blockIdx.x * 8 + (threadIdx.x >> 6);
    int col = threadIdx.x & 63;
    if (n >= N) return;
    float acc = bc[col];
    const float* aa = aggA + n * 64;
    const float* ar = aggRH + n * 64;
#pragma unroll 8
    for (int k = 0; k < 64; ++k) acc += aa[k] * sW[k * 64 + col];
#pragma unroll 8
    for (int k = 0; k < 64; ++k) acc += ar[k] * sW[(64 + k) * 64 + col];
    float c = tanhf(acc);
    float z = Z[n * 64 + col];
    float hv = h[n * 64 + col];
    h[n * 64 + col] = z * hv + (1.0f - z) * c;
}

// out[n] = h1[n,:] . Wout + bout ; one 64-lane wave per node
__global__ void out_k(const float* __restrict__ h1, const float* __restrict__ Wout,
                      const float* __restrict__ bout, float* __restrict__ out, int N) {
    int i = blockIdx.x * blockDim.x + threadIdx.x;
    int n = i >> 6;
    if (n >= N) return;
    int k = i & 63;
    float p = h1[n * 64 + k] * Wout[k];
    for (int off = 32; off > 0; off >>= 1) p += __shfl_down(p, off);
    if (k == 0) out[n] = p + bout[0];
}

extern "C" void kernel_launch(void* const* d_in, const int* in_sizes, int n_in,
                              void* d_out, int out_size, void* d_ws, size_t ws_size,
                              hipStream_t stream) {
    const float* x   = (const float*)d_in[0];
    const int*   ei  = (const int*)d_in[1];
    const float* ew  = (const float*)d_in[2];
    const float* Wg0 = (const float*)d_in[3];
    const float* bg0 = (const float*)d_in[4];
    const float* Wc0 = (const float*)d_in[5];
    const float* bc0 = (const float*)d_in[6];
    const float* Wg1 = (const float*)d_in[7];
    const float* bg1 = (const float*)d_in[8];
    const float* Wc1 = (const float*)d_in[9];
    const float* bc1 = (const float*)d_in[10];
    const float* Wout = (const float*)d_in[11];
    const float* bout = (const float*)d_in[12];

    const int N = in_sizes[0] / FT;
    const int E = in_sizes[2];
    const int* src = ei;
    const int* dst = ei + E;

    float* ws   = (float*)d_ws;
    float* aggX = ws;                    // N*96
    float* h0   = aggX + (size_t)N * FT; // N*64
    float* h1   = h0 + (size_t)N * 64;
    float* A    = h1 + (size_t)N * 64;
    float* B    = A + (size_t)N * 64;
    float* Z    = B + (size_t)N * 64;
    float* RH   = Z + (size_t)N * 64;

    const size_t nh4 = (size_t)N * 64 * sizeof(float);
    const int sgrid64 = (E * 64 + 255) / 256;
    const int sgrid96 = (E * FT + 255) / 256;
    const int g128 = (N + 3) / 4;   // 512-thread blocks, 4 nodes/block
    const int g64  = (N + 7) / 8;   // 512-thread blocks, 8 nodes/block

    hipMemsetAsync(aggX, 0, (size_t)N * FT * sizeof(float), stream);
    hipMemsetAsync(h0, 0, 2 * nh4, stream);  // h0 and h1 contiguous
    scatter96<<<sgrid96, 256, 0, stream>>>(x, src, dst, ew, aggX, E);

    for (int t = 0; t < TSTEPS; ++t) {
        // ---- layer 0 ----
        hipMemsetAsync(A, 0, nh4, stream);
        scatter64<<<sgrid64, 256, 0, stream>>>(h0, src, dst, ew, A, E);
        gate0_k<<<g128, 512, 0, stream>>>(aggX, t, A, Wg0, bg0, h0, Z, RH, N);
        hipMemsetAsync(B, 0, nh4, stream);
        scatter64<<<sgrid64, 256, 0, stream>>>(RH, src, dst, ew, B, E);
        cand0_k<<<g64, 512, 0, stream>>>(aggX, t, B, Wc0, bc0, Z, h0, N);
        // ---- layer 1 ----
        hipMemsetAsync(A, 0, nh4, stream);
        scatter64<<<sgrid64, 256, 0, stream>>>(h0, src, dst, ew, A, E);
        hipMemsetAsync(B, 0, nh4, stream);
        scatter64<<<sgrid64, 256, 0, stream>>>(h1, src, dst, ew, B, E);
        gate1_k<<<g128, 512, 0, stream>>>(A, B, Wg1, bg1, h1, Z, RH, N);
        hipMemsetAsync(B, 0, nh4, stream);
        scatter64<<<sgrid64, 256, 0, stream>>>(RH, src, dst, ew, B, E);
        cand1_k<<<g64, 512, 0, stream>>>(A, B, Wc1, bc1, Z, h1, N);
    }

    out_k<<<((N * 64) + 255) / 256, 256, 0, stream>>>(h1, Wout, bout, (float*)d_out, N);
}

// Round 2
// 7163.230 us; speedup vs baseline: 2.0822x; 2.0822x over previous
//
#include <hip/hip_runtime.h>

// TGCN 2-layer, T=12, F=8, H=64, N=50k, E=800k.
// R2: replace atomic scatters (3.07B memory-side atomics -> 11ms) with a
// per-launch CSR build (counting sort, ~1.6M int atomics) + gather kernels.
// gconv is linear => split concat: precompute gconv(x) for all t once.

#define FT 96      // F*T
#define TSTEPS 12

// ---------------- CSR build ----------------
__global__ void hist_k(const int* __restrict__ dst, int* __restrict__ deg, int E) {
    int e = blockIdx.x * blockDim.x + threadIdx.x;
    if (e < E) atomicAdd(&deg[dst[e]], 1);
}

// single-block exclusive scan over N (<= a few 100k), writes rowptr[0..N] and cursor copy
__global__ __launch_bounds__(1024) void scan_k(const int* __restrict__ deg,
                                               int* __restrict__ rowptr,
                                               int* __restrict__ cursor, int N) {
    __shared__ int sm[1024];
    __shared__ int s_carry;
    if (threadIdx.x == 0) s_carry = 0;
    __syncthreads();
    for (int base = 0; base < N; base += 1024) {
        int i = base + (int)threadIdx.x;
        int v = (i < N) ? deg[i] : 0;
        sm[threadIdx.x] = v;
        __syncthreads();
        for (int off = 1; off < 1024; off <<= 1) {
            int t = (threadIdx.x >= (unsigned)off) ? sm[threadIdx.x - off] : 0;
            __syncthreads();
            sm[threadIdx.x] += t;
            __syncthreads();
        }
        int incl = sm[threadIdx.x];
        int total = sm[1023];
        int excl = incl - v + s_carry;
        if (i < N) { rowptr[i] = excl; cursor[i] = excl; }
        __syncthreads();
        if (threadIdx.x == 0) s_carry += total;
        __syncthreads();
    }
    if (threadIdx.x == 0) rowptr[N] = s_carry;
}

__global__ void fill_k(const int* __restrict__ src, const int* __restrict__ dst,
                       const float* __restrict__ ew, int* __restrict__ cursor,
                       int* __restrict__ csr_src, float* __restrict__ csr_w, int E) {
    int e = blockIdx.x * blockDim.x + threadIdx.x;
    if (e >= E) return;
    int pos = atomicAdd(&cursor[dst[e]], 1);
    csr_src[pos] = src[e];
    csr_w[pos] = ew[e];
}

// ---------------- gathers (1 wave per node, lane = channel) ----------------
__global__ __launch_bounds__(256) void gather1_k(
    const float* __restrict__ feat, const int* __restrict__ rowptr,
    const int* __restrict__ csr_src, const float* __restrict__ csr_w,
    float* __restrict__ out, int N) {
    int n = blockIdx.x * 4 + (threadIdx.x >> 6);
    if (n >= N) return;
    int c = threadIdx.x & 63;
    int beg = rowptr[n], end = rowptr[n + 1];
    int deg = end - beg;
    float acc = 0.f;
    int sv = 0; float wv = 0.f;
    if (c < deg) { sv = csr_src[beg + c]; wv = csr_w[beg + c]; }
    int m = deg < 64 ? deg : 64;
#pragma unroll 4
    for (int j = 0; j < m; ++j) {
        int s = __shfl(sv, j);
        float w = __shfl(wv, j);
        acc += w * feat[s * 64 + c];
    }
    for (int e = beg + 64; e < end; ++e) {   // deg>64 tail (rare)
        acc += csr_w[e] * feat[csr_src[e] * 64 + c];
    }
    out[n * 64 + c] = acc;
}

// dual gather: A=gconv(f0), B=gconv(f1) sharing one edge pass
__global__ __launch_bounds__(256) void gather2_k(
    const float* __restrict__ f0, const float* __restrict__ f1,
    const int* __restrict__ rowptr, const int* __restrict__ csr_src,
    const float* __restrict__ csr_w,
    float* __restrict__ outA, float* __restrict__ outB, int N) {
    int n = blockIdx.x * 4 + (threadIdx.x >> 6);
    if (n >= N) return;
    int c = threadIdx.x & 63;
    int beg = rowptr[n], end = rowptr[n + 1];
    int deg = end - beg;
    float a0 = 0.f, a1 = 0.f;
    int sv = 0; float wv = 0.f;
    if (c < deg) { sv = csr_src[beg + c]; wv = csr_w[beg + c]; }
    int m = deg < 64 ? deg : 64;
#pragma unroll 2
    for (int j = 0; j < m; ++j) {
        int s = __shfl(sv, j);
        float w = __shfl(wv, j);
        a0 += w * f0[s * 64 + c];
        a1 += w * f1[s * 64 + c];
    }
    for (int e = beg + 64; e < end; ++e) {
        int s = csr_src[e]; float w = csr_w[e];
        a0 += w * f0[s * 64 + c];
        a1 += w * f1[s * 64 + c];
    }
    outA[n * 64 + c] = a0;
    outB[n * 64 + c] = a1;
}

// gather over x: 96 channels/node; lane c covers c and (c<32 ? 64+c : -)
__global__ __launch_bounds__(256) void gather96_k(
    const float* __restrict__ x, const int* __restrict__ rowptr,
    const int* __restrict__ csr_src, const float* __restrict__ csr_w,
    float* __restrict__ out, int N) {
    int n = blockIdx.x * 4 + (threadIdx.x >> 6);
    if (n >= N) return;
    int c = threadIdx.x & 63;
    int beg = rowptr[n], end = rowptr[n + 1];
    int deg = end - beg;
    float a0 = 0.f, a1 = 0.f;
    int sv = 0; float wv = 0.f;
    if (c < deg) { sv = csr_src[beg + c]; wv = csr_w[beg + c]; }
    int m = deg < 64 ? deg : 64;
#pragma unroll 2
    for (int j = 0; j < m; ++j) {
        int s = __shfl(sv, j);
        float w = __shfl(wv, j);
        const float* row = x + s * FT;
        a0 += w * row[c];
        if (c < 32) a1 += w * row[64 + c];
    }
    for (int e = beg + 64; e < end; ++e) {
        int s = csr_src[e]; float w = csr_w[e];
        const float* row = x + s * FT;
        a0 += w * row[c];
        if (c < 32) a1 += w * row[64 + c];
    }
    out[n * FT + c] = a0;
    if (c < 32) out[n * FT + 64 + c] = a1;
}

// ---------------- dense cell kernels ----------------
__global__ __launch_bounds__(512) void gate0_k(
    const float* __restrict__ aggX, int t, const float* __restrict__ aggH,
    const float* __restrict__ Wg, const float* __restrict__ bg,
    const float* __restrict__ h, float* __restrict__ Z, float* __restrict__ RH, int N) {
    __shared__ float sW[72 * 128];
    for (int j = threadIdx.x; j < 72 * 128; j += 512) sW[j] = Wg[j];
    __syncthreads();
    int n = blockIdx.x * 4 + (threadIdx.x >> 7);
    int col = threadIdx.x & 127;
    if (n >= N) return;
    float acc = bg[col];
    const float* ax = aggX + n * FT;
#pragma unroll
    for (int f = 0; f < 8; ++f) acc += ax[f * TSTEPS + t] * sW[f * 128 + col];
    const float* ah = aggH + n * 64;
#pragma unroll 8
    for (int k = 0; k < 64; ++k) acc += ah[k] * sW[(8 + k) * 128 + col];
    float s = 1.0f / (1.0f + __expf(-acc));
    if (col < 64) RH[n * 64 + col] = s * h[n * 64 + col];
    else          Z[n * 64 + (col - 64)] = s;
}

__global__ __launch_bounds__(512) void cand0_k(
    const float* __restrict__ aggX, int t, const float* __restrict__ aggRH,
    const float* __restrict__ Wc, const float* __restrict__ bc,
    const float* __restrict__ Z, float* __restrict__ h, int N) {
    __shared__ float sW[72 * 64];
    for (int j = threadIdx.x; j < 72 * 64; j += 512) sW[j] = Wc[j];
    __syncthreads();
    int n = blockIdx.x * 8 + (threadIdx.x >> 6);
    int col = threadIdx.x & 63;
    if (n >= N) return;
    float acc = bc[col];
    const float* ax = aggX + n * FT;
#pragma unroll
    for (int f = 0; f < 8; ++f) acc += ax[f * TSTEPS + t] * sW[f * 64 + col];
    const float* ar = aggRH + n * 64;
#pragma unroll 8
    for (int k = 0; k < 64; ++k) acc += ar[k] * sW[(8 + k) * 64 + col];
    float c = tanhf(acc);
    float z = Z[n * 64 + col];
    float hv = h[n * 64 + col];
    h[n * 64 + col] = z * hv + (1.0f - z) * c;
}

__global__ __launch_bounds__(512) void gate1_k(
    const float* __restrict__ aggA, const float* __restrict__ aggB,
    const float* __restrict__ Wg, const float* __restrict__ bg,
    const float* __restrict__ h, float* __restrict__ Z, float* __restrict__ RH, int N) {
    __shared__ float sW[128 * 128];
    for (int j = threadIdx.x; j < 128 * 128; j += 512) sW[j] = Wg[j];
    __syncthreads();
    int n = blockIdx.x * 4 + (threadIdx.x >> 7);
    int col = threadIdx.x & 127;
    if (n >= N) return;
    float acc = bg[col];
    const float* aa = aggA + n * 64;
    const float* ab = aggB + n * 64;
#pragma unroll 8
    for (int k = 0; k < 64; ++k) acc += aa[k] * sW[k * 128 + col];
#pragma unroll 8
    for (int k = 0; k < 64; ++k) acc += ab[k] * sW[(64 + k) * 128 + col];
    float s = 1.0f / (1.0f + __expf(-acc));
    if (col < 64) RH[n * 64 + col] = s * h[n * 64 + col];
    else          Z[n * 64 + (col - 64)] = s;
}

__global__ __launch_bounds__(512) void cand1_k(
    const float* __restrict__ aggA, const float* __restrict__ aggRH,
    const float* __restrict__ Wc, const float* __restrict__ bc,
    const float* __restrict__ Z, float* __restrict__ h, int N) {
    __shared__ float sW[128 * 64];
    for (int j = threadIdx.x; j < 128 * 64; j += 512) sW[j] = Wc[j];
    __syncthreads();
    int n = blockIdx.x * 8 + (threadIdx.x >> 6);
    int col = threadIdx.x & 63;
    if (n >= N) return;
    float acc = bc[col];
    const float* aa = aggA + n * 64;
    const float* ar = aggRH + n * 64;
#pragma unroll 8
    for (int k = 0; k < 64; ++k) acc += aa[k] * sW[k * 64 + col];
#pragma unroll 8
    for (int k = 0; k < 64; ++k) acc += ar[k] * sW[(64 + k) * 64 + col];
    float c = tanhf(acc);
    float z = Z[n * 64 + col];
    float hv = h[n * 64 + col];
    h[n * 64 + col] = z * hv + (1.0f - z) * c;
}

__global__ void out_k(const float* __restrict__ h1, const float* __restrict__ Wout,
                      const float* __restrict__ bout, float* __restrict__ out, int N) {
    int i = blockIdx.x * blockDim.x + threadIdx.x;
    int n = i >> 6;
    if (n >= N) return;
    int k = i & 63;
    float p = h1[n * 64 + k] * Wout[k];
    for (int off = 32; off > 0; off >>= 1) p += __shfl_down(p, off);
    if (k == 0) out[n] = p + bout[0];
}

extern "C" void kernel_launch(void* const* d_in, const int* in_sizes, int n_in,
                              void* d_out, int out_size, void* d_ws, size_t ws_size,
                              hipStream_t stream) {
    const float* x   = (const float*)d_in[0];
    const int*   ei  = (const int*)d_in[1];
    const float* ew  = (const float*)d_in[2];
    const float* Wg0 = (const float*)d_in[3];
    const float* bg0 = (const float*)d_in[4];
    const float* Wc0 = (const float*)d_in[5];
    const float* bc0 = (const float*)d_in[6];
    const float* Wg1 = (const float*)d_in[7];
    const float* bg1 = (const float*)d_in[8];
    const float* Wc1 = (const float*)d_in[9];
    const float* bc1 = (const float*)d_in[10];
    const float* Wout = (const float*)d_in[11];
    const float* bout = (const float*)d_in[12];

    const int N = in_sizes[0] / FT;
    const int E = in_sizes[2];
    const int* src = ei;
    const int* dst = ei + E;

    // workspace layout
    char* p = (char*)d_ws;
    int*   deg     = (int*)p;               p += (size_t)N * 4;
    int*   rowptr  = (int*)p;               p += (size_t)(N + 1) * 4;
    int*   cursor  = (int*)p;               p += (size_t)N * 4;
    int*   csr_src = (int*)p;               p += (size_t)E * 4;
    float* csr_w   = (float*)p;             p += (size_t)E * 4;
    float* aggX    = (float*)p;             p += (size_t)N * FT * 4;
    float* h0      = (float*)p;             p += (size_t)N * 64 * 4;
    float* h1      = (float*)p;             p += (size_t)N * 64 * 4;
    float* A       = (float*)p;             p += (size_t)N * 64 * 4;
    float* B       = (float*)p;             p += (size_t)N * 64 * 4;
    float* Z       = (float*)p;             p += (size_t)N * 64 * 4;
    float* RH      = (float*)p;             p += (size_t)N * 64 * 4;

    const int gE   = (E + 255) / 256;
    const int gN4  = (N + 3) / 4;    // 256-thread gather blocks, 4 nodes each
    const int g128 = (N + 3) / 4;    // 512-thread, 4 nodes (128 cols)
    const int g64  = (N + 7) / 8;    // 512-thread, 8 nodes (64 cols)

    // CSR build (once per launch; ws re-poisoned each call)
    hipMemsetAsync(deg, 0, (size_t)N * 4, stream);
    hipMemsetAsync(h0, 0, (size_t)N * 64 * 2 * 4, stream);  // h0,h1 contiguous
    hist_k<<<gE, 256, 0, stream>>>(dst, deg, E);
    scan_k<<<1, 1024, 0, stream>>>(deg, rowptr, cursor, N);
    fill_k<<<gE, 256, 0, stream>>>(src, dst, ew, cursor, csr_src, csr_w, E);
    gather96_k<<<gN4, 256, 0, stream>>>(x, rowptr, csr_src, csr_w, aggX, N);

    for (int t = 0; t < TSTEPS; ++t) {
        // layer 0
        gather1_k<<<gN4, 256, 0, stream>>>(h0, rowptr, csr_src, csr_w, A, N);
        gate0_k<<<g128, 512, 0, stream>>>(aggX, t, A, Wg0, bg0, h0, Z, RH, N);
        gather1_k<<<gN4, 256, 0, stream>>>(RH, rowptr, csr_src, csr_w, B, N);
        cand0_k<<<g64, 512, 0, stream>>>(aggX, t, B, Wc0, bc0, Z, h0, N);
        // layer 1
        gather2_k<<<gN4, 256, 0, stream>>>(h0, h1, rowptr, csr_src, csr_w, A, B, N);
        gate1_k<<<g128, 512, 0, stream>>>(A, B, Wg1, bg1, h1, Z, RH, N);
        gather1_k<<<gN4, 256, 0, stream>>>(RH, rowptr, csr_src, csr_w, B, N);
        cand1_k<<<g64, 512, 0, stream>>>(A, B, Wc1, bc1, Z, h1, N);
    }

    out_k<<<((N * 64) + 255) / 256, 256, 0, stream>>>(h1, Wout, bout, (float*)d_out, N);
}

// Round 3
// 6225.850 us; speedup vs baseline: 2.3957x; 1.1506x over previous
//
#include <hip/hip_runtime.h>

// TGCN 2-layer, T=12, F=8, H=64, N=50k, E=800k.
// R3: fuse gather+dense per cell-phase (4 kernels/step). Dense compute is
// transposed: lane=node, weights via wave-uniform scalar loads, agg rows in
// LDS (stride-65 padding -> 2-way bank aliasing, free). Outputs staged in
// LDS for coalesced global writes.

#define FT 96
#define TSTEPS 12

// ---------------- CSR build ----------------
__global__ void hist_k(const int* __restrict__ dst, int* __restrict__ deg, int E) {
    int e = blockIdx.x * blockDim.x + threadIdx.x;
    if (e < E) atomicAdd(&deg[dst[e]], 1);
}

__global__ __launch_bounds__(1024) void scan_k(const int* __restrict__ deg,
                                               int* __restrict__ rowptr,
                                               int* __restrict__ cursor, int N) {
    __shared__ int sm[1024];
    __shared__ int s_carry;
    if (threadIdx.x == 0) s_carry = 0;
    __syncthreads();
    for (int base = 0; base < N; base += 1024) {
        int i = base + (int)threadIdx.x;
        int v = (i < N) ? deg[i] : 0;
        sm[threadIdx.x] = v;
        __syncthreads();
        for (int off = 1; off < 1024; off <<= 1) {
            int t = (threadIdx.x >= (unsigned)off) ? sm[threadIdx.x - off] : 0;
            __syncthreads();
            sm[threadIdx.x] += t;
            __syncthreads();
        }
        int incl = sm[threadIdx.x];
        int total = sm[1023];
        int excl = incl - v + s_carry;
        if (i < N) { rowptr[i] = excl; cursor[i] = excl; }
        __syncthreads();
        if (threadIdx.x == 0) s_carry += total;
        __syncthreads();
    }
    if (threadIdx.x == 0) rowptr[N] = s_carry;
}

__global__ void fill_k(const int* __restrict__ src, const int* __restrict__ dst,
                       const float* __restrict__ ew, int* __restrict__ cursor,
                       int* __restrict__ csr_src, float* __restrict__ csr_w, int E) {
    int e = blockIdx.x * blockDim.x + threadIdx.x;
    if (e >= E) return;
    int pos = atomicAdd(&cursor[dst[e]], 1);
    csr_src[pos] = src[e];
    csr_w[pos] = ew[e];
}

// gather of x (96 ch/node), writes TRANSPOSED aggXt[t][n][f] for coalesced
// per-step reads in the cell kernels.
__global__ __launch_bounds__(256) void gather96_k(
    const float* __restrict__ x, const int* __restrict__ rowptr,
    const int* __restrict__ csr_src, const float* __restrict__ csr_w,
    float* __restrict__ aggXt, int N) {
    int n = blockIdx.x * 4 + (threadIdx.x >> 6);
    if (n >= N) return;
    int c = threadIdx.x & 63;
    int beg = rowptr[n], end = rowptr[n + 1];
    int deg = end - beg;
    float a0 = 0.f, a1 = 0.f;
    int sv = 0; float wv = 0.f;
    if (c < deg) { sv = csr_src[beg + c]; wv = csr_w[beg + c]; }
    int m = deg < 64 ? deg : 64;
    for (int j = 0; j < m; ++j) {
        int s = __shfl(sv, j);
        float w = __shfl(wv, j);
        const float* row = x + (size_t)s * FT;
        a0 += w * row[c];
        if (c < 32) a1 += w * row[64 + c];
    }
    for (int e = beg + 64; e < end; ++e) {
        int s = csr_src[e]; float w = csr_w[e];
        const float* row = x + (size_t)s * FT;
        a0 += w * row[c];
        if (c < 32) a1 += w * row[64 + c];
    }
    { int f = c / 12, tt = c - f * 12;
      aggXt[((size_t)tt * N + n) * 8 + f] = a0; }
    if (c < 32) { int cc = 64 + c; int f = cc / 12, tt = cc - f * 12;
      aggXt[((size_t)tt * N + n) * 8 + f] = a1; }
}

// ---------------- fused cell kernels ----------------
__device__ __forceinline__ float gather_node(const float* __restrict__ feat,
    const int* __restrict__ csr_src, const float* __restrict__ csr_w,
    int beg, int end, int c) {
    int deg = end - beg;
    float acc = 0.f;
    int sv = 0; float wv = 0.f;
    if (c < deg) { sv = csr_src[beg + c]; wv = csr_w[beg + c]; }
    int m = deg < 64 ? deg : 64;
    for (int j = 0; j < m; ++j) {
        int s = __shfl(sv, j);
        float w = __shfl(wv, j);
        acc += w * feat[(size_t)s * 64 + c];
    }
    for (int e = beg + 64; e < end; ++e)
        acc += csr_w[e] * feat[(size_t)csr_src[e] * 64 + c];
    return acc;
}

// Layer-0 gate: gather(h0) -> sA; rz = sigmoid([aggX_t, sA] @ Wg0 + bg0);
// RH = r*h0, Z = z
__global__ __launch_bounds__(256) void l0_gate(
    const float* __restrict__ h0, const float* __restrict__ aggXt, int t,
    const int* __restrict__ rowptr, const int* __restrict__ csr_src,
    const float* __restrict__ csr_w, const float* __restrict__ Wg,
    const float* __restrict__ bg, float* __restrict__ Z,
    float* __restrict__ RH, int N) {
    __shared__ float sA[64 * 65];
    __shared__ float sX[64 * 9];
    __shared__ float sZ[64 * 65];
    const int tid = threadIdx.x;
    const int lane = tid & 63;
    const int wid = __builtin_amdgcn_readfirstlane(tid >> 6);
    const int nb = blockIdx.x * 64;
    // phase A: gather + aggX load
    for (int i = 0; i < 16; ++i) {
        int nl = wid * 16 + i, n = nb + nl;
        if (n < N) {
            int beg = rowptr[n], end = rowptr[n + 1];
            sA[nl * 65 + lane] = gather_node(h0, csr_src, csr_w, beg, end, lane);
        }
    }
    for (int i = tid; i < 512; i += 256) {
        int nl = i >> 3, f = i & 7, n = nb + nl;
        sX[nl * 9 + f] = (n < N) ? aggXt[((size_t)t * N + n) * 8 + f] : 0.f;
    }
    __syncthreads();
    // phase B: lane=node, 32 cols per wave, weights scalar-loaded
    const int col0 = wid * 32;
    float acc[32];
#pragma unroll
    for (int j = 0; j < 32; ++j) acc[j] = bg[col0 + j];
#pragma unroll
    for (int f = 0; f < 8; ++f) {
        float a = sX[lane * 9 + f];
        const float* __restrict__ w = Wg + f * 128 + col0;
#pragma unroll
        for (int j = 0; j < 32; ++j) acc[j] = fmaf(a, w[j], acc[j]);
    }
    for (int k = 0; k < 64; ++k) {
        float a = sA[lane * 65 + k];
        const float* __restrict__ w = Wg + (8 + k) * 128 + col0;
#pragma unroll
        for (int j = 0; j < 32; ++j) acc[j] = fmaf(a, w[j], acc[j]);
    }
#pragma unroll
    for (int j = 0; j < 32; ++j) acc[j] = 1.f / (1.f + __expf(-acc[j]));
    __syncthreads();
    // stage: r -> sA, z -> sZ
    if (col0 < 64) {
#pragma unroll
        for (int j = 0; j < 32; ++j) sA[lane * 65 + col0 + j] = acc[j];
    } else {
#pragma unroll
        for (int j = 0; j < 32; ++j) sZ[lane * 65 + (col0 - 64) + j] = acc[j];
    }
    __syncthreads();
    // phase C: coalesced writes
    for (int i = tid; i < 4096; i += 256) {
        int nl = i >> 6, cc = i & 63, n = nb + nl;
        if (n < N) {
            float hv = h0[(size_t)n * 64 + cc];
            RH[(size_t)n * 64 + cc] = sA[nl * 65 + cc] * hv;
            Z[(size_t)n * 64 + cc] = sZ[nl * 65 + cc];
        }
    }
}

// Layer-0 cand: gather(RH) -> sA; c = tanh([aggX_t, sA] @ Wc0 + bc0);
// h0 = z*h0 + (1-z)*c
__global__ __launch_bounds__(256) void l0_cand(
    const float* __restrict__ RH, const float* __restrict__ aggXt, int t,
    const int* __restrict__ rowptr, const int* __restrict__ csr_src,
    const float* __restrict__ csr_w, const float* __restrict__ Wc,
    const float* __restrict__ bc, const float* __restrict__ Z,
    float* __restrict__ h0, int N) {
    __shared__ float sA[64 * 65];
    __shared__ float sX[64 * 9];
    const int tid = threadIdx.x;
    const int lane = tid & 63;
    const int wid = __builtin_amdgcn_readfirstlane(tid >> 6);
    const int nb = blockIdx.x * 64;
    for (int i = 0; i < 16; ++i) {
        int nl = wid * 16 + i, n = nb + nl;
        if (n < N) {
            int beg = rowptr[n], end = rowptr[n + 1];
            sA[nl * 65 + lane] = gather_node(RH, csr_src, csr_w, beg, end, lane);
        }
    }
    for (int i = tid; i < 512; i += 256) {
        int nl = i >> 3, f = i & 7, n = nb + nl;
        sX[nl * 9 + f] = (n < N) ? aggXt[((size_t)t * N + n) * 8 + f] : 0.f;
    }
    __syncthreads();
    const int col0 = wid * 16;
    float acc[16];
#pragma unroll
    for (int j = 0; j < 16; ++j) acc[j] = bc[col0 + j];
#pragma unroll
    for (int f = 0; f < 8; ++f) {
        float a = sX[lane * 9 + f];
        const float* __restrict__ w = Wc + f * 64 + col0;
#pragma unroll
        for (int j = 0; j < 16; ++j) acc[j] = fmaf(a, w[j], acc[j]);
    }
    for (int k = 0; k < 64; ++k) {
        float a = sA[lane * 65 + k];
        const float* __restrict__ w = Wc + (8 + k) * 64 + col0;
#pragma unroll
        for (int j = 0; j < 16; ++j) acc[j] = fmaf(a, w[j], acc[j]);
    }
#pragma unroll
    for (int j = 0; j < 16; ++j) {
        float e = __expf(2.f * acc[j]);
        acc[j] = 1.f - 2.f / (e + 1.f);
    }
    __syncthreads();
#pragma unroll
    for (int j = 0; j < 16; ++j) sA[lane * 65 + col0 + j] = acc[j];
    __syncthreads();
    for (int i = tid; i < 4096; i += 256) {
        int nl = i >> 6, cc = i & 63, n = nb + nl;
        if (n < N) {
            float z = Z[(size_t)n * 64 + cc];
            float hv = h0[(size_t)n * 64 + cc];
            h0[(size_t)n * 64 + cc] = z * hv + (1.f - z) * sA[nl * 65 + cc];
        }
    }
}

// Layer-1 gate: dual gather(h0,h1) -> sA,sB; dump sA (=gconv(h0new)) to Aglob;
// rz = sigmoid([sA, sB] @ Wg1 + bg1); RH = r*h1, Z = z
__global__ __launch_bounds__(256) void l1_gate(
    const float* __restrict__ h0, const float* __restrict__ h1,
    const int* __restrict__ rowptr, const int* __restrict__ csr_src,
    const float* __restrict__ csr_w, const float* __restrict__ Wg,
    const float* __restrict__ bg, float* __restrict__ Aglob,
    float* __restrict__ Z, float* __restrict__ RH, int N) {
    __shared__ float sA[64 * 65];
    __shared__ float sB[64 * 65];
    const int tid = threadIdx.x;
    const int lane = tid & 63;
    const int wid = __builtin_amdgcn_readfirstlane(tid >> 6);
    const int nb = blockIdx.x * 64;
    for (int i = 0; i < 16; ++i) {
        int nl = wid * 16 + i, n = nb + nl;
        if (n < N) {
            int beg = rowptr[n], end = rowptr[n + 1];
            int deg = end - beg;
            float a0 = 0.f, a1 = 0.f;
            int sv = 0; float wv = 0.f;
            if (lane < deg) { sv = csr_src[beg + lane]; wv = csr_w[beg + lane]; }
            int m = deg < 64 ? deg : 64;
            for (int j = 0; j < m; ++j) {
                int s = __shfl(sv, j);
                float w = __shfl(wv, j);
                a0 += w * h0[(size_t)s * 64 + lane];
                a1 += w * h1[(size_t)s * 64 + lane];
            }
            for (int e = beg + 64; e < end; ++e) {
                int s = csr_src[e]; float w = csr_w[e];
                a0 += w * h0[(size_t)s * 64 + lane];
                a1 += w * h1[(size_t)s * 64 + lane];
            }
            sA[nl * 65 + lane] = a0;
            sB[nl * 65 + lane] = a1;
        }
    }
    __syncthreads();
    const int col0 = wid * 32;
    float acc[32];
#pragma unroll
    for (int j = 0; j < 32; ++j) acc[j] = bg[col0 + j];
    for (int k = 0; k < 64; ++k) {
        float a = sA[lane * 65 + k];
        const float* __restrict__ w = Wg + k * 128 + col0;
#pragma unroll
        for (int j = 0; j < 32; ++j) acc[j] = fmaf(a, w[j], acc[j]);
    }
    for (int k = 0; k < 64; ++k) {
        float a = sB[lane * 65 + k];
        const float* __restrict__ w = Wg + (64 + k) * 128 + col0;
#pragma unroll
        for (int j = 0; j < 32; ++j) acc[j] = fmaf(a, w[j], acc[j]);
    }
#pragma unroll
    for (int j = 0; j < 32; ++j) acc[j] = 1.f / (1.f + __expf(-acc[j]));
    __syncthreads();
    // C1: dump gconv(h0new) for reuse by l1_cand
    for (int i = tid; i < 4096; i += 256) {
        int nl = i >> 6, cc = i & 63, n = nb + nl;
        if (n < N) Aglob[(size_t)n * 64 + cc] = sA[nl * 65 + cc];
    }
    __syncthreads();
    if (col0 < 64) {
#pragma unroll
        for (int j = 0; j < 32; ++j) sA[lane * 65 + col0 + j] = acc[j];
    } else {
#pragma unroll
        for (int j = 0; j < 32; ++j) sB[lane * 65 + (col0 - 64) + j] = acc[j];
    }
    __syncthreads();
    for (int i = tid; i < 4096; i += 256) {
        int nl = i >> 6, cc = i & 63, n = nb + nl;
        if (n < N) {
            float hv = h1[(size_t)n * 64 + cc];
            RH[(size_t)n * 64 + cc] = sA[nl * 65 + cc] * hv;
            Z[(size_t)n * 64 + cc] = sB[nl * 65 + cc];
        }
    }
}

// Layer-1 cand: gather(RH) -> sA; load Aglob -> sB;
// c = tanh([sB, sA] @ Wc1 + bc1); h1 = z*h1 + (1-z)*c
__global__ __launch_bounds__(256) void l1_cand(
    const float* __restrict__ RH, const float* __restrict__ Aglob,
    const int* __restrict__ rowptr, const int* __restrict__ csr_src,
    const float* __restrict__ csr_w, const float* __restrict__ Wc,
    const float* __restrict__ bc, const float* __restrict__ Z,
    float* __restrict__ h1, int N) {
    __shared__ float sA[64 * 65];
    __shared__ float sB[64 * 65];
    const int tid = threadIdx.x;
    const int lane = tid & 63;
    const int wid = __builtin_amdgcn_readfirstlane(tid >> 6);
    const int nb = blockIdx.x * 64;
    for (int i = 0; i < 16; ++i) {
        int nl = wid * 16 + i, n = nb + nl;
        if (n < N) {
            int beg = rowptr[n], end = rowptr[n + 1];
            sA[nl * 65 + lane] = gather_node(RH, csr_src, csr_w, beg, end, lane);
        }
    }
    for (int i = tid; i < 4096; i += 256) {
        int nl = i >> 6, k = i & 63, n = nb + nl;
        sB[nl * 65 + k] = (n < N) ? Aglob[(size_t)n * 64 + k] : 0.f;
    }
    __syncthreads();
    const int col0 = wid * 16;
    float acc[16];
#pragma unroll
    for (int j = 0; j < 16; ++j) acc[j] = bc[col0 + j];
    for (int k = 0; k < 64; ++k) {
        float a = sB[lane * 65 + k];
        const float* __restrict__ w = Wc + k * 64 + col0;
#pragma unroll
        for (int j = 0; j < 16; ++j) acc[j] = fmaf(a, w[j], acc[j]);
    }
    for (int k = 0; k < 64; ++k) {
        float a = sA[lane * 65 + k];
        const float* __restrict__ w = Wc + (64 + k) * 64 + col0;
#pragma unroll
        for (int j = 0; j < 16; ++j) acc[j] = fmaf(a, w[j], acc[j]);
    }
#pragma unroll
    for (int j = 0; j < 16; ++j) {
        float e = __expf(2.f * acc[j]);
        acc[j] = 1.f - 2.f / (e + 1.f);
    }
    __syncthreads();
#pragma unroll
    for (int j = 0; j < 16; ++j) sA[lane * 65 + col0 + j] = acc[j];
    __syncthreads();
    for (int i = tid; i < 4096; i += 256) {
        int nl = i >> 6, cc = i & 63, n = nb + nl;
        if (n < N) {
            float z = Z[(size_t)n * 64 + cc];
            float hv = h1[(size_t)n * 64 + cc];
            h1[(size_t)n * 64 + cc] = z * hv + (1.f - z) * sA[nl * 65 + cc];
        }
    }
}

__global__ void out_k(const float* __restrict__ h1, const float* __restrict__ Wout,
                      const float* __restrict__ bout, float* __restrict__ out, int N) {
    int i = blockIdx.x * blockDim.x + threadIdx.x;
    int n = i >> 6;
    if (n >= N) return;
    int k = i & 63;
    float p = h1[(size_t)n * 64 + k] * Wout[k];
    for (int off = 32; off > 0; off >>= 1) p += __shfl_down(p, off);
    if (k == 0) out[n] = p + bout[0];
}

extern "C" void kernel_launch(void* const* d_in, const int* in_sizes, int n_in,
                              void* d_out, int out_size, void* d_ws, size_t ws_size,
                              hipStream_t stream) {
    const float* x   = (const float*)d_in[0];
    const int*   ei  = (const int*)d_in[1];
    const float* ew  = (const float*)d_in[2];
    const float* Wg0 = (const float*)d_in[3];
    const float* bg0 = (const float*)d_in[4];
    const float* Wc0 = (const float*)d_in[5];
    const float* bc0 = (const float*)d_in[6];
    const float* Wg1 = (const float*)d_in[7];
    const float* bg1 = (const float*)d_in[8];
    const float* Wc1 = (const float*)d_in[9];
    const float* bc1 = (const float*)d_in[10];
    const float* Wout = (const float*)d_in[11];
    const float* bout = (const float*)d_in[12];

    const int N = in_sizes[0] / FT;
    const int E = in_sizes[2];
    const int* src = ei;
    const int* dst = ei + E;

    char* p = (char*)d_ws;
    int*   deg     = (int*)p;   p += (size_t)N * 4;
    int*   rowptr  = (int*)p;   p += (size_t)(N + 1) * 4;
    int*   cursor  = (int*)p;   p += (size_t)N * 4;
    int*   csr_src = (int*)p;   p += (size_t)E * 4;
    float* csr_w   = (float*)p; p += (size_t)E * 4;
    float* aggXt   = (float*)p; p += (size_t)N * FT * 4;  // [t][n][f]
    float* h0      = (float*)p; p += (size_t)N * 64 * 4;
    float* h1      = (float*)p; p += (size_t)N * 64 * 4;
    float* A       = (float*)p; p += (size_t)N * 64 * 4;
    float* Z       = (float*)p; p += (size_t)N * 64 * 4;
    float* RH      = (float*)p; p += (size_t)N * 64 * 4;

    const int gE  = (E + 255) / 256;
    const int gN4 = (N + 3) / 4;
    const int gN64 = (N + 63) / 64;

    hipMemsetAsync(deg, 0, (size_t)N * 4, stream);
    hipMemsetAsync(h0, 0, (size_t)N * 64 * 2 * 4, stream);  // h0,h1 contiguous
    hist_k<<<gE, 256, 0, stream>>>(dst, deg, E);
    scan_k<<<1, 1024, 0, stream>>>(deg, rowptr, cursor, N);
    fill_k<<<gE, 256, 0, stream>>>(src, dst, ew, cursor, csr_src, csr_w, E);
    gather96_k<<<gN4, 256, 0, stream>>>(x, rowptr, csr_src, csr_w, aggXt, N);

    for (int t = 0; t < TSTEPS; ++t) {
        l0_gate<<<gN64, 256, 0, stream>>>(h0, aggXt, t, rowptr, csr_src, csr_w,
                                          Wg0, bg0, Z, RH, N);
        l0_cand<<<gN64, 256, 0, stream>>>(RH, aggXt, t, rowptr, csr_src, csr_w,
                                          Wc0, bc0, Z, h0, N);
        l1_gate<<<gN64, 256, 0, stream>>>(h0, h1, rowptr, csr_src, csr_w,
                                          Wg1, bg1, A, Z, RH, N);
        l1_cand<<<gN64, 256, 0, stream>>>(RH, A, rowptr, csr_src, csr_w,
                                          Wc1, bc1, Z, h1, N);
    }

    out_k<<<((N * 64) + 255) / 256, 256, 0, stream>>>(h1, Wout, bout, (float*)d_out, N);
}

// Round 4
// 3416.367 us; speedup vs baseline: 4.3658x; 1.8224x over previous
//
#include <hip/hip_runtime.h>
#include <hip/hip_fp16.h>

// TGCN 2-layer, T=12, F=8, H=64, N=50k, E=800k.
// R4: gathered features stored as fp16 mirrors (128B = 1 cache line per edge
// row, halves gather traffic); gather edge-loop unrolled (8 loads in flight).
// fp32 masters kept for elementwise GRU updates.

#define FT 96
#define TSTEPS 12

// ---------------- CSR build ----------------
__global__ void hist_k(const int* __restrict__ dst, int* __restrict__ deg, int E) {
    int e = blockIdx.x * blockDim.x + threadIdx.x;
    if (e < E) atomicAdd(&deg[dst[e]], 1);
}

// exclusive scan over deg -> rowptr; rewrites deg as cursor copy
__global__ __launch_bounds__(1024) void scan_k(int* __restrict__ deg,
                                               int* __restrict__ rowptr, int N) {
    __shared__ int sm[1024];
    __shared__ int s_carry;
    if (threadIdx.x == 0) s_carry = 0;
    __syncthreads();
    for (int base = 0; base < N; base += 1024) {
        int i = base + (int)threadIdx.x;
        int v = (i < N) ? deg[i] : 0;
        sm[threadIdx.x] = v;
        __syncthreads();
        for (int off = 1; off < 1024; off <<= 1) {
            int t = (threadIdx.x >= (unsigned)off) ? sm[threadIdx.x - off] : 0;
            __syncthreads();
            sm[threadIdx.x] += t;
            __syncthreads();
        }
        int incl = sm[threadIdx.x];
        int total = sm[1023];
        int excl = incl - v + s_carry;
        if (i < N) { rowptr[i] = excl; deg[i] = excl; }  // deg becomes cursor
        __syncthreads();
        if (threadIdx.x == 0) s_carry += total;
        __syncthreads();
    }
    if (threadIdx.x == 0) rowptr[N] = s_carry;
}

__global__ void fill_k(const int* __restrict__ src, const int* __restrict__ dst,
                       const float* __restrict__ ew, int* __restrict__ cursor,
                       int* __restrict__ csr_src, float* __restrict__ csr_w, int E) {
    int e = blockIdx.x * blockDim.x + threadIdx.x;
    if (e >= E) return;
    int pos = atomicAdd(&cursor[dst[e]], 1);
    csr_src[pos] = src[e];
    csr_w[pos] = ew[e];
}

// gather of x (fp32, one-time), writes transposed aggXt[t][n][f]
__global__ __launch_bounds__(256) void gather96_k(
    const float* __restrict__ x, const int* __restrict__ rowptr,
    const int* __restrict__ csr_src, const float* __restrict__ csr_w,
    float* __restrict__ aggXt, int N) {
    int n = blockIdx.x * 4 + (threadIdx.x >> 6);
    if (n >= N) return;
    int c = threadIdx.x & 63;
    int beg = rowptr[n], end = rowptr[n + 1];
    int deg = end - beg;
    float a0 = 0.f, a1 = 0.f;
    int sv = 0; float wv = 0.f;
    if (c < deg) { sv = csr_src[beg + c]; wv = csr_w[beg + c]; }
    int m = deg < 64 ? deg : 64;
    int m4 = (m + 3) & ~3;
#pragma unroll 4
    for (int j = 0; j < m4; ++j) {
        int s = __shfl(sv, j);
        float w = __shfl(wv, j);
        const float* row = x + (size_t)s * FT;
        a0 += w * row[c];
        if (c < 32) a1 += w * row[64 + c];
    }
    for (int e = beg + 64; e < end; ++e) {
        int s = csr_src[e]; float w = csr_w[e];
        const float* row = x + (size_t)s * FT;
        a0 += w * row[c];
        if (c < 32) a1 += w * row[64 + c];
    }
    { int f = c / 12, tt = c - f * 12;
      aggXt[((size_t)tt * N + n) * 8 + f] = a0; }
    if (c < 32) { int cc = 64 + c; int f = cc / 12, tt = cc - f * 12;
      aggXt[((size_t)tt * N + n) * 8 + f] = a1; }
}

// ---------------- fp16 gather helpers ----------------
__device__ __forceinline__ float gather_node_h(const __half* __restrict__ feat,
    const int* __restrict__ csr_src, const float* __restrict__ csr_w,
    int beg, int end, int c) {
    int deg = end - beg;
    float acc = 0.f;
    int sv = 0; float wv = 0.f;
    if (c < deg) { sv = csr_src[beg + c]; wv = csr_w[beg + c]; }
    int m = deg < 64 ? deg : 64;
    int m8 = (m + 7) & ~7;   // lanes >= deg carry wv=0, sv=0 (safe addr)
#pragma unroll 8
    for (int j = 0; j < m8; ++j) {
        int s = __shfl(sv, j);
        float w = __shfl(wv, j);
        acc += w * __half2float(feat[(size_t)s * 64 + c]);
    }
    for (int e = beg + 64; e < end; ++e)
        acc += csr_w[e] * __half2float(feat[(size_t)csr_src[e] * 64 + c]);
    return acc;
}

// ---------------- fused cell kernels ----------------
// Layer-0 gate: gather(h0h) -> sA; rz = sigmoid([aggX_t, sA] @ Wg0 + bg0);
// RHh = r*h0 (fp16), Z = z
__global__ __launch_bounds__(256) void l0_gate(
    const float* __restrict__ h0f, const __half* __restrict__ h0h,
    const float* __restrict__ aggXt, int t,
    const int* __restrict__ rowptr, const int* __restrict__ csr_src,
    const float* __restrict__ csr_w, const float* __restrict__ Wg,
    const float* __restrict__ bg, float* __restrict__ Z,
    __half* __restrict__ RHh, int N) {
    __shared__ float sA[64 * 65];
    __shared__ float sX[64 * 9];
    __shared__ float sZ[64 * 65];
    const int tid = threadIdx.x;
    const int lane = tid & 63;
    const int wid = __builtin_amdgcn_readfirstlane(tid >> 6);
    const int nb = blockIdx.x * 64;
    for (int i = 0; i < 16; ++i) {
        int nl = wid * 16 + i, n = nb + nl;
        if (n < N) {
            int beg = rowptr[n], end = rowptr[n + 1];
            sA[nl * 65 + lane] = gather_node_h(h0h, csr_src, csr_w, beg, end, lane);
        }
    }
    for (int i = tid; i < 512; i += 256) {
        int nl = i >> 3, f = i & 7, n = nb + nl;
        sX[nl * 9 + f] = (n < N) ? aggXt[((size_t)t * N + n) * 8 + f] : 0.f;
    }
    __syncthreads();
    const int col0 = wid * 32;
    float acc[32];
#pragma unroll
    for (int j = 0; j < 32; ++j) acc[j] = bg[col0 + j];
#pragma unroll
    for (int f = 0; f < 8; ++f) {
        float a = sX[lane * 9 + f];
        const float* __restrict__ w = Wg + f * 128 + col0;
#pragma unroll
        for (int j = 0; j < 32; ++j) acc[j] = fmaf(a, w[j], acc[j]);
    }
    for (int k = 0; k < 64; ++k) {
        float a = sA[lane * 65 + k];
        const float* __restrict__ w = Wg + (8 + k) * 128 + col0;
#pragma unroll
        for (int j = 0; j < 32; ++j) acc[j] = fmaf(a, w[j], acc[j]);
    }
#pragma unroll
    for (int j = 0; j < 32; ++j) acc[j] = 1.f / (1.f + __expf(-acc[j]));
    __syncthreads();
    if (col0 < 64) {
#pragma unroll
        for (int j = 0; j < 32; ++j) sA[lane * 65 + col0 + j] = acc[j];
    } else {
#pragma unroll
        for (int j = 0; j < 32; ++j) sZ[lane * 65 + (col0 - 64) + j] = acc[j];
    }
    __syncthreads();
    for (int i = tid; i < 4096; i += 256) {
        int nl = i >> 6, cc = i & 63, n = nb + nl;
        if (n < N) {
            float hv = h0f[(size_t)n * 64 + cc];
            RHh[(size_t)n * 64 + cc] = __float2half(sA[nl * 65 + cc] * hv);
            Z[(size_t)n * 64 + cc] = sZ[nl * 65 + cc];
        }
    }
}

// Layer-0 cand: gather(RHh) -> sA; c = tanh([aggX_t, sA] @ Wc0 + bc0);
// h0 = z*h0 + (1-z)*c  (writes fp32 + fp16 mirror)
__global__ __launch_bounds__(256) void l0_cand(
    const __half* __restrict__ RHh, const float* __restrict__ aggXt, int t,
    const int* __restrict__ rowptr, const int* __restrict__ csr_src,
    const float* __restrict__ csr_w, const float* __restrict__ Wc,
    const float* __restrict__ bc, const float* __restrict__ Z,
    float* __restrict__ h0f, __half* __restrict__ h0h, int N) {
    __shared__ float sA[64 * 65];
    __shared__ float sX[64 * 9];
    const int tid = threadIdx.x;
    const int lane = tid & 63;
    const int wid = __builtin_amdgcn_readfirstlane(tid >> 6);
    const int nb = blockIdx.x * 64;
    for (int i = 0; i < 16; ++i) {
        int nl = wid * 16 + i, n = nb + nl;
        if (n < N) {
            int beg = rowptr[n], end = rowptr[n + 1];
            sA[nl * 65 + lane] = gather_node_h(RHh, csr_src, csr_w, beg, end, lane);
        }
    }
    for (int i = tid; i < 512; i += 256) {
        int nl = i >> 3, f = i & 7, n = nb + nl;
        sX[nl * 9 + f] = (n < N) ? aggXt[((size_t)t * N + n) * 8 + f] : 0.f;
    }
    __syncthreads();
    const int col0 = wid * 16;
    float acc[16];
#pragma unroll
    for (int j = 0; j < 16; ++j) acc[j] = bc[col0 + j];
#pragma unroll
    for (int f = 0; f < 8; ++f) {
        float a = sX[lane * 9 + f];
        const float* __restrict__ w = Wc + f * 64 + col0;
#pragma unroll
        for (int j = 0; j < 16; ++j) acc[j] = fmaf(a, w[j], acc[j]);
    }
    for (int k = 0; k < 64; ++k) {
        float a = sA[lane * 65 + k];
        const float* __restrict__ w = Wc + (8 + k) * 64 + col0;
#pragma unroll
        for (int j = 0; j < 16; ++j) acc[j] = fmaf(a, w[j], acc[j]);
    }
#pragma unroll
    for (int j = 0; j < 16; ++j) {
        float e = __expf(2.f * acc[j]);
        acc[j] = 1.f - 2.f / (e + 1.f);
    }
    __syncthreads();
#pragma unroll
    for (int j = 0; j < 16; ++j) sA[lane * 65 + col0 + j] = acc[j];
    __syncthreads();
    for (int i = tid; i < 4096; i += 256) {
        int nl = i >> 6, cc = i & 63, n = nb + nl;
        if (n < N) {
            float z = Z[(size_t)n * 64 + cc];
            float hv = h0f[(size_t)n * 64 + cc];
            float nh = z * hv + (1.f - z) * sA[nl * 65 + cc];
            h0f[(size_t)n * 64 + cc] = nh;
            h0h[(size_t)n * 64 + cc] = __float2half(nh);
        }
    }
}

// Layer-1 gate: dual gather(h0h,h1h) -> sA,sB; dump sA (=gconv(h0new)) -> Aglob;
// rz = sigmoid([sA,sB] @ Wg1 + bg1); RHh = r*h1, Z = z
__global__ __launch_bounds__(256) void l1_gate(
    const __half* __restrict__ h0h, const float* __restrict__ h1f,
    const __half* __restrict__ h1h,
    const int* __restrict__ rowptr, const int* __restrict__ csr_src,
    const float* __restrict__ csr_w, const float* __restrict__ Wg,
    const float* __restrict__ bg, float* __restrict__ Aglob,
    float* __restrict__ Z, __half* __restrict__ RHh, int N) {
    __shared__ float sA[64 * 65];
    __shared__ float sB[64 * 65];
    const int tid = threadIdx.x;
    const int lane = tid & 63;
    const int wid = __builtin_amdgcn_readfirstlane(tid >> 6);
    const int nb = blockIdx.x * 64;
    for (int i = 0; i < 16; ++i) {
        int nl = wid * 16 + i, n = nb + nl;
        if (n < N) {
            int beg = rowptr[n], end = rowptr[n + 1];
            int deg = end - beg;
            float a0 = 0.f, a1 = 0.f;
            int sv = 0; float wv = 0.f;
            if (lane < deg) { sv = csr_src[beg + lane]; wv = csr_w[beg + lane]; }
            int m = deg < 64 ? deg : 64;
            int m4 = (m + 3) & ~3;
#pragma unroll 4
            for (int j = 0; j < m4; ++j) {
                int s = __shfl(sv, j);
                float w = __shfl(wv, j);
                a0 += w * __half2float(h0h[(size_t)s * 64 + lane]);
                a1 += w * __half2float(h1h[(size_t)s * 64 + lane]);
            }
            for (int e = beg + 64; e < end; ++e) {
                int s = csr_src[e]; float w = csr_w[e];
                a0 += w * __half2float(h0h[(size_t)s * 64 + lane]);
                a1 += w * __half2float(h1h[(size_t)s * 64 + lane]);
            }
            sA[nl * 65 + lane] = a0;
            sB[nl * 65 + lane] = a1;
        }
    }
    __syncthreads();
    const int col0 = wid * 32;
    float acc[32];
#pragma unroll
    for (int j = 0; j < 32; ++j) acc[j] = bg[col0 + j];
    for (int k = 0; k < 64; ++k) {
        float a = sA[lane * 65 + k];
        const float* __restrict__ w = Wg + k * 128 + col0;
#pragma unroll
        for (int j = 0; j < 32; ++j) acc[j] = fmaf(a, w[j], acc[j]);
    }
    for (int k = 0; k < 64; ++k) {
        float a = sB[lane * 65 + k];
        const float* __restrict__ w = Wg + (64 + k) * 128 + col0;
#pragma unroll
        for (int j = 0; j < 32; ++j) acc[j] = fmaf(a, w[j], acc[j]);
    }
#pragma unroll
    for (int j = 0; j < 32; ++j) acc[j] = 1.f / (1.f + __expf(-acc[j]));
    __syncthreads();
    for (int i = tid; i < 4096; i += 256) {
        int nl = i >> 6, cc = i & 63, n = nb + nl;
        if (n < N) Aglob[(size_t)n * 64 + cc] = sA[nl * 65 + cc];
    }
    __syncthreads();
    if (col0 < 64) {
#pragma unroll
        for (int j = 0; j < 32; ++j) sA[lane * 65 + col0 + j] = acc[j];
    } else {
#pragma unroll
        for (int j = 0; j < 32; ++j) sB[lane * 65 + (col0 - 64) + j] = acc[j];
    }
    __syncthreads();
    for (int i = tid; i < 4096; i += 256) {
        int nl = i >> 6, cc = i & 63, n = nb + nl;
        if (n < N) {
            float hv = h1f[(size_t)n * 64 + cc];
            RHh[(size_t)n * 64 + cc] = __float2half(sA[nl * 65 + cc] * hv);
            Z[(size_t)n * 64 + cc] = sB[nl * 65 + cc];
        }
    }
}

// Layer-1 cand: gather(RHh) -> sA; load Aglob -> sB;
// c = tanh([sB, sA] @ Wc1 + bc1); h1 = z*h1 + (1-z)*c  (fp32 + fp16 mirror)
__global__ __launch_bounds__(256) void l1_cand(
    const __half* __restrict__ RHh, const float* __restrict__ Aglob,
    const int* __restrict__ rowptr, const int* __restrict__ csr_src,
    const float* __restrict__ csr_w, const float* __restrict__ Wc,
    const float* __restrict__ bc, const float* __restrict__ Z,
    float* __restrict__ h1f, __half* __restrict__ h1h, int N) {
    __shared__ float sA[64 * 65];
    __shared__ float sB[64 * 65];
    const int tid = threadIdx.x;
    const int lane = tid & 63;
    const int wid = __builtin_amdgcn_readfirstlane(tid >> 6);
    const int nb = blockIdx.x * 64;
    for (int i = 0; i < 16; ++i) {
        int nl = wid * 16 + i, n = nb + nl;
        if (n < N) {
            int beg = rowptr[n], end = rowptr[n + 1];
            sA[nl * 65 + lane] = gather_node_h(RHh, csr_src, csr_w, beg, end, lane);
        }
    }
    for (int i = tid; i < 4096; i += 256) {
        int nl = i >> 6, k = i & 63, n = nb + nl;
        sB[nl * 65 + k] = (n < N) ? Aglob[(size_t)n * 64 + k] : 0.f;
    }
    __syncthreads();
    const int col0 = wid * 16;
    float acc[16];
#pragma unroll
    for (int j = 0; j < 16; ++j) acc[j] = bc[col0 + j];
    for (int k = 0; k < 64; ++k) {
        float a = sB[lane * 65 + k];
        const float* __restrict__ w = Wc + k * 64 + col0;
#pragma unroll
        for (int j = 0; j < 16; ++j) acc[j] = fmaf(a, w[j], acc[j]);
    }
    for (int k = 0; k < 64; ++k) {
        float a = sA[lane * 65 + k];
        const float* __restrict__ w = Wc + (64 + k) * 64 + col0;
#pragma unroll
        for (int j = 0; j < 16; ++j) acc[j] = fmaf(a, w[j], acc[j]);
    }
#pragma unroll
    for (int j = 0; j < 16; ++j) {
        float e = __expf(2.f * acc[j]);
        acc[j] = 1.f - 2.f / (e + 1.f);
    }
    __syncthreads();
#pragma unroll
    for (int j = 0; j < 16; ++j) sA[lane * 65 + col0 + j] = acc[j];
    __syncthreads();
    for (int i = tid; i < 4096; i += 256) {
        int nl = i >> 6, cc = i & 63, n = nb + nl;
        if (n < N) {
            float z = Z[(size_t)n * 64 + cc];
            float hv = h1f[(size_t)n * 64 + cc];
            float nh = z * hv + (1.f - z) * sA[nl * 65 + cc];
            h1f[(size_t)n * 64 + cc] = nh;
            h1h[(size_t)n * 64 + cc] = __float2half(nh);
        }
    }
}

__global__ void out_k(const float* __restrict__ h1, const float* __restrict__ Wout,
                      const float* __restrict__ bout, float* __restrict__ out, int N) {
    int i = blockIdx.x * blockDim.x + threadIdx.x;
    int n = i >> 6;
    if (n >= N) return;
    int k = i & 63;
    float p = h1[(size_t)n * 64 + k] * Wout[k];
    for (int off = 32; off > 0; off >>= 1) p += __shfl_down(p, off);
    if (k == 0) out[n] = p + bout[0];
}

extern "C" void kernel_launch(void* const* d_in, const int* in_sizes, int n_in,
                              void* d_out, int out_size, void* d_ws, size_t ws_size,
                              hipStream_t stream) {
    const float* x   = (const float*)d_in[0];
    const int*   ei  = (const int*)d_in[1];
    const float* ew  = (const float*)d_in[2];
    const float* Wg0 = (const float*)d_in[3];
    const float* bg0 = (const float*)d_in[4];
    const float* Wc0 = (const float*)d_in[5];
    const float* bc0 = (const float*)d_in[6];
    const float* Wg1 = (const float*)d_in[7];
    const float* bg1 = (const float*)d_in[8];
    const float* Wc1 = (const float*)d_in[9];
    const float* bc1 = (const float*)d_in[10];
    const float* Wout = (const float*)d_in[11];
    const float* bout = (const float*)d_in[12];

    const int N = in_sizes[0] / FT;
    const int E = in_sizes[2];
    const int* src = ei;
    const int* dst = ei + E;

    char* p = (char*)d_ws;
    int*    deg     = (int*)p;    p += (size_t)N * 4;        // doubles as cursor
    int*    rowptr  = (int*)p;    p += (size_t)(N + 1) * 4;
    int*    csr_src = (int*)p;    p += (size_t)E * 4;
    float*  csr_w   = (float*)p;  p += (size_t)E * 4;
    float*  aggXt   = (float*)p;  p += (size_t)N * FT * 4;   // [t][n][f]
    float*  h0f     = (float*)p;  p += (size_t)N * 64 * 4;
    float*  h1f     = (float*)p;  p += (size_t)N * 64 * 4;
    float*  A       = (float*)p;  p += (size_t)N * 64 * 4;
    float*  Z       = (float*)p;  p += (size_t)N * 64 * 4;
    __half* h0h     = (__half*)p; p += (size_t)N * 64 * 2;
    __half* h1h     = (__half*)p; p += (size_t)N * 64 * 2;
    __half* RHh     = (__half*)p; p += (size_t)N * 64 * 2;

    const int gE  = (E + 255) / 256;
    const int gN4 = (N + 3) / 4;
    const int gN64 = (N + 63) / 64;

    hipMemsetAsync(deg, 0, (size_t)N * 4, stream);
    hipMemsetAsync(h0f, 0, (size_t)N * 64 * 2 * 4, stream);  // h0f,h1f contiguous
    hipMemsetAsync(h0h, 0, (size_t)N * 64 * 2 * 2, stream);  // h0h,h1h contiguous
    hist_k<<<gE, 256, 0, stream>>>(dst, deg, E);
    scan_k<<<1, 1024, 0, stream>>>(deg, rowptr, N);
    fill_k<<<gE, 256, 0, stream>>>(src, dst, ew, deg, csr_src, csr_w, E);
    gather96_k<<<gN4, 256, 0, stream>>>(x, rowptr, csr_src, csr_w, aggXt, N);

    for (int t = 0; t < TSTEPS; ++t) {
        l0_gate<<<gN64, 256, 0, stream>>>(h0f, h0h, aggXt, t, rowptr, csr_src, csr_w,
                                          Wg0, bg0, Z, RHh, N);
        l0_cand<<<gN64, 256, 0, stream>>>(RHh, aggXt, t, rowptr, csr_src, csr_w,
                                          Wc0, bc0, Z, h0f, h0h, N);
        l1_gate<<<gN64, 256, 0, stream>>>(h0h, h1f, h1h, rowptr, csr_src, csr_w,
                                          Wg1, bg1, A, Z, RHh, N);
        l1_cand<<<gN64, 256, 0, stream>>>(RHh, A, rowptr, csr_src, csr_w,
                                          Wc1, bc1, Z, h1f, h1h, N);
    }

    out_k<<<((N * 64) + 255) / 256, 256, 0, stream>>>(h1f, Wout, bout, (float*)d_out, N);
}